// Round 9
// baseline (123.088 us; speedup 1.0000x reference)
//
#include <hip/hip_runtime.h>

#define NVV   778
#define NSEG  16
#define SEGSZ 49
#define GRIDN 32
#define BATCH 128
#define NPTS  (NSEG * SEGSZ)           // 784
#define VOLSZ (GRIDN * GRIDN * GRIDN)  // 32768 floats = 128 KB
#define NBLK  512                       // 2 blocks (one per z-half) x 256 CU-seqs
#define VPB   16                        // volumes per block sequence

// z-halves: half 0 = slabs 0..16 (68 KB) serves z0 in [-1,15]
//           half 1 = slabs 16..31 (64 KB) serves z0 in [16,31]
#define HALF_MAX_FLOATS (17 * 1024)

typedef __attribute__((address_space(1))) const void* as1_t;
typedef __attribute__((address_space(3))) void* as3_t;

// Inter-block TLP replaces software pipelining: 2 co-resident blocks per CU
// (68 KB LDS each, 16 waves each). While one block drains vmcnt at its
// barrier, the other block's waves keep streaming — the compiler can't
// defeat that. Simple per-task structure: stream -> sync -> tap -> sync.
__global__ __launch_bounds__(1024, 8) void sample_kernel(
    const float* __restrict__ vertices, const int* __restrict__ seg,
    const float* __restrict__ phiR, const float* __restrict__ phiL,
    float* __restrict__ loss)
{
    __shared__ __align__(16) float piece[HALF_MAX_FLOATS];
    __shared__ float4 sbox[VPB];
    __shared__ float wsum[16];

    const int tid  = threadIdx.x;
    const int bx   = blockIdx.x;
    const int half = bx >> 8;            // 0: low z, 1: high z
    const int base = bx & 255;
    const int k    = base & (NSEG - 1);  // constant per block
    const int wv   = tid >> 6;
    const int lane = tid & 63;

    const int   nch  = half ? 64 : 68;           // 1 KB chunks to stream
    const int   soff = half ? 16 * 1024 : 0;     // float offset into volume

    auto phiPtr = [&](int it) {
        int vid  = base + 256 * it;
        int b    = (vid >> 4) & (BATCH - 1);
        int pass = vid >> 11;                    // NSEG*BATCH = 2048
        return (pass == 0 ? phiR : phiL) + ((size_t)k * BATCH + b) * VOLSZ;
    };

    // ---- prologue: point index + all 16 boxes (wave w -> volume w) ----
    int pvi = (tid < NPTS) ? seg[tid] : 0;
    {
        int vid  = base + 256 * wv;
        int bb   = (vid >> 4) & (BATCH - 1);
        int boxSide = ((vid >> 11) == 0) ? 0 : 1;    // opposite of sampled side
        bool act = lane < SEGSZ;
        int vi = act ? seg[k * SEGSZ + lane] : 0;
        const float* v = vertices + (((size_t)bb * 2 + boxSide) * NVV + vi) * 3;
        float x = v[0], y = v[1], z = v[2];
        float mnx = act ? x : 1e30f, mxx = act ? x : -1e30f;
        float mny = act ? y : 1e30f, mxy = act ? y : -1e30f;
        float mnz = act ? z : 1e30f, mxz = act ? z : -1e30f;
        #pragma unroll
        for (int m = 32; m; m >>= 1) {
            mnx = fminf(mnx, __shfl_xor(mnx, m));
            mxx = fmaxf(mxx, __shfl_xor(mxx, m));
            mny = fminf(mny, __shfl_xor(mny, m));
            mxy = fmaxf(mxy, __shfl_xor(mxy, m));
            mnz = fminf(mnz, __shfl_xor(mnz, m));
            mxz = fmaxf(mxz, __shfl_xor(mxz, m));
        }
        if (lane == 0) {
            float ext = fmaxf(fmaxf(mxx - mnx, mxy - mny), mxz - mnz);
            sbox[wv] = make_float4(0.5f * (mnx + mxx), 0.5f * (mny + mxy),
                                   0.5f * (mnz + mxz), 1.0f / (0.55f * ext));
        }
    }

    for (int it = 0; it < VPB; ++it) {
        const float* src = phiPtr(it) + soff;

        // ---- stream this half-volume into LDS (async DMA, issued first) --
        for (int c = wv; c < nch; c += 16)
            __builtin_amdgcn_global_load_lds(
                (as1_t)(src + c * 256 + lane * 4),
                (as3_t)(piece + c * 256), 16, 0, 0);

        // ---- scattered point-vertex load (latency hides under stream) ----
        float pvx = 0.f, pvy = 0.f, pvz = 0.f;
        if (tid < NPTS) {
            int vid  = base + 256 * it;
            int b    = (vid >> 4) & (BATCH - 1);
            int srcS = (vid >> 11) == 0 ? 1 : 0;
            const float* v = vertices + (((size_t)b * 2 + srcS) * NVV + pvi) * 3;
            pvx = v[0]; pvy = v[1]; pvz = v[2];
        }

        __syncthreads();   // piece resident; sbox visible (prologue or prev)

        // ---- taps for points whose z-cell lies in this half ----
        float acc = 0.f;
        if (tid < NPTS) {
            float4 b4 = sbox[it];
            float fx = ((pvx - b4.x) * b4.w + 1.f) * 15.5f;
            float fy = ((pvy - b4.y) * b4.w + 1.f) * 15.5f;
            float fz = ((pvz - b4.z) * b4.w + 1.f) * 15.5f;
            bool inxy = (fx > -1.f && fx < 32.f && fy > -1.f && fy < 32.f);
            bool inz  = half ? (fz >= 16.f && fz < 32.f)
                             : (fz > -1.f && fz < 16.f);
            if (inxy && inz) {
                float x0f = floorf(fx), y0f = floorf(fy), z0f = floorf(fz);
                float wx = fx - x0f, wy = fy - y0f, wz = fz - z0f;
                int x0 = (int)x0f, y0 = (int)y0f, z0 = (int)z0f;
                int zr = z0 - (half ? 16 : 0);
                bool z0ok = half ? true : (z0 >= 0);
                bool z1ok = half ? (z0 < 31) : true;
                #pragma unroll
                for (int dz = 0; dz < 2; ++dz) {
                    if (!(dz ? z1ok : z0ok)) continue;
                    float wwz = dz ? wz : 1.f - wz;
                    const float* slab = piece + (zr + dz) * (GRIDN * GRIDN);
                    #pragma unroll
                    for (int dy = 0; dy < 2; ++dy) {
                        int yy = y0 + dy;
                        if (yy < 0 || yy >= GRIDN) continue;
                        float wzy = wwz * (dy ? wy : 1.f - wy);
                        const float* row = slab + yy * GRIDN;
                        #pragma unroll
                        for (int dx = 0; dx < 2; ++dx) {
                            int xx = x0 + dx;
                            if (xx < 0 || xx >= GRIDN) continue;
                            acc += wzy * (dx ? wx : 1.f - wx) * row[xx];
                        }
                    }
                }
            }
        }

        // ---- block reduction ----
        #pragma unroll
        for (int off = 32; off; off >>= 1)
            acc += __shfl_down(acc, off);
        if (lane == 0) wsum[wv] = acc;
        __syncthreads();   // wsum visible; all waves done with piece
        if (tid == 0) {
            float tot = 0.f;
            #pragma unroll
            for (int i = 0; i < 16; ++i) tot += wsum[i];
            int vid = base + 256 * it;
            atomicAdd(loss + ((vid >> 4) & (BATCH - 1)), tot * 0.25f);
        }
    }
}

extern "C" void kernel_launch(void* const* d_in, const int* in_sizes, int n_in,
                              void* d_out, int out_size, void* d_ws, size_t ws_size,
                              hipStream_t stream) {
    const float* vertices = (const float*)d_in[0];
    const float* phiR     = (const float*)d_in[1];
    const float* phiL     = (const float*)d_in[2];
    const int*   seg      = (const int*)d_in[3];
    float* loss = (float*)d_out;

    hipMemsetAsync(d_out, 0, (size_t)out_size * sizeof(float), stream);

    sample_kernel<<<NBLK, 1024, 0, stream>>>(vertices, seg, phiR, phiL, loss);
}